// Round 8
// baseline (212.794 us; speedup 1.0000x reference)
//
#include <hip/hip_runtime.h>

#define B_  4
#define S_  2048
#define D_  1024
#define N_  (B_*S_)
#define SCALE 0.03125f
#define NEGINF (-3.0e38f)

typedef unsigned short u16;
typedef __attribute__((ext_vector_type(8))) short short8;
typedef __attribute__((ext_vector_type(4))) float floatx4;

__device__ __forceinline__ u16 f2bf(float f) {           // RNE float->bf16
    unsigned int u = __float_as_uint(f);
    u += 0x7FFFu + ((u >> 16) & 1u);
    return (u16)(u >> 16);
}
__device__ __forceinline__ float bf2f(u16 h) {
    return __uint_as_float((unsigned int)h << 16);
}

__device__ __forceinline__ void gl_lds16(const void* g, void* l) {
    __builtin_amdgcn_global_load_lds(
        (const __attribute__((address_space(1))) unsigned int*)g,
        (__attribute__((address_space(3))) unsigned int*)l, 16, 0, 0);
}

// bijective chunked XCD swizzle (nwg % 8 == 0)
__device__ __forceinline__ int xcd_chunk(int bid, int nwg) {
    return (bid & 7) * (nwg >> 3) + (bid >> 3);
}

// ---------------- fused casts ----------------
__global__ __launch_bounds__(256) void cast_fused(const float* __restrict__ x,
                                                  const float* __restrict__ Wq, const float* __restrict__ Wk,
                                                  const float* __restrict__ Wv,
                                                  u16* __restrict__ xb, u16* __restrict__ Wqb,
                                                  u16* __restrict__ Wkb, u16* __restrict__ Wvt) {
    __shared__ float t[32][33];
    const int blk = blockIdx.x;
    if (blk < 5120) {
        const float* src; u16* dst; size_t i;
        if (blk < 4096)      { src = x;  dst = xb;  i = (size_t)blk * 2048; }
        else if (blk < 4608) { src = Wq; dst = Wqb; i = (size_t)(blk - 4096) * 2048; }
        else                 { src = Wk; dst = Wkb; i = (size_t)(blk - 4608) * 2048; }
        i += (size_t)threadIdx.x * 8;
        float4 a = *(const float4*)&src[i];
        float4 b = *(const float4*)&src[i + 4];
        short8 o;
        o[0]=f2bf(a.x); o[1]=f2bf(a.y); o[2]=f2bf(a.z); o[3]=f2bf(a.w);
        o[4]=f2bf(b.x); o[5]=f2bf(b.y); o[6]=f2bf(b.z); o[7]=f2bf(b.w);
        *(short8*)&dst[i] = o;
    } else {
        const int tb = blk - 5120;                 // 0..1023
        const int c = threadIdx.x & 31, r0 = threadIdx.x >> 5;
        const int i0 = (tb >> 5) * 32, j0 = (tb & 31) * 32;
#pragma unroll
        for (int rr = 0; rr < 4; ++rr)
            t[r0 + rr * 8][c] = Wv[(size_t)(i0 + r0 + rr * 8) * D_ + j0 + c];
        __syncthreads();
#pragma unroll
        for (int rr = 0; rr < 4; ++rr)
            Wvt[(size_t)(j0 + r0 + rr * 8) * D_ + i0 + c] = f2bf(t[c][r0 + rr * 8]);
    }
}

// =====================================================================================
// LDS layout: per buffer, per matrix, two k-half planes [kk][row][32].
// Within a row, 4 slots of 8 bf16; slot holds global k-octet (slot ^ ((row>>1)&3)).
// Swizzle on the GLOBAL source (gl_lds dest linear) + same involution on ds_read addr.
// Single-barrier K-loop (r5/r7-verified): { vmcnt(0); barrier; stage(t+1); compute t }.
// At 2 blocks/CU co-residency the other block's waves hide the drain+barrier bubble
// (m103/m114 implicit wave-level overlap) -- that is the point of this round.
// =====================================================================================

// ================= 128x128 core: 4 waves (256 thr), single barrier/tile (r5-verified) =========
__device__ __forceinline__ void mfma_nt_128(const u16* __restrict__ A, int lda,
                                            const u16* __restrict__ Bp, int ldb,
                                            int m0, int n0, int kext,
                                            u16* Sh, floatx4 acc[4][4])
{
    const int tid  = threadIdx.x;          // 0..255
    const int lane = tid & 63;
    const int lr   = lane & 15, quad = lane >> 4;
    const int wm   = ((tid >> 6) & 1) * 64, wn = (tid >> 7) * 64;
    const int nt   = kext >> 6;

    auto stage8 = [&](int t) {             // 8 gl_lds / thread = full 2x(128x64) tile
#pragma unroll
        for (int h = 0; h < 8; ++h) {
            const int kk = h >> 2, mat = (h >> 1) & 1, half = h & 1;
            const int idx = tid * 8;       // 0..2047
            const int row = half * 64 + (idx >> 5);
            const int s   = (idx & 31) >> 3;
            const int gk  = (t << 6) + kk * 32 + ((s ^ ((row >> 1) & 3)) << 3);
            u16* dst = Sh + (t & 1) * 16384 + mat * 8192 + kk * 4096 + half * 2048 + idx;
            const u16* src = mat ? &Bp[(size_t)(n0 + row) * ldb + gk]
                                 : &A [(size_t)(m0 + row) * lda + gk];
            gl_lds16(src, dst);
        }
    };

    stage8(0);
    for (int t = 0; t < nt; ++t) {
        asm volatile("s_waitcnt vmcnt(0)" ::: "memory");
        __builtin_amdgcn_s_barrier();
        if (t + 1 < nt) stage8(t + 1);
        const u16* buf = Sh + (t & 1) * 16384;
#pragma unroll
        for (int kk = 0; kk < 2; ++kk) {
            short8 af[4], bf[4];
#pragma unroll
            for (int i = 0; i < 4; ++i) {
                const int ar = wm + i * 16 + lr;
                af[i] = *(const short8*)&buf[kk * 4096 + ar * 32 + ((quad ^ ((ar >> 1) & 3)) << 3)];
                const int br = wn + i * 16 + lr;
                bf[i] = *(const short8*)&buf[8192 + kk * 4096 + br * 32 + ((quad ^ ((br >> 1) & 3)) << 3)];
            }
            __builtin_amdgcn_s_setprio(1);
#pragma unroll
            for (int i = 0; i < 4; ++i)
#pragma unroll
                for (int j = 0; j < 4; ++j)
                    acc[i][j] = __builtin_amdgcn_mfma_f32_16x16x32_bf16(af[i], bf[j], acc[i][j], 0, 0, 0);
            __builtin_amdgcn_s_setprio(0);
        }
    }
}

#define EPI_VARS                                              \
    const int lane = threadIdx.x & 63;                        \
    const int lr = lane & 15, quad = lane >> 4;               \
    const int wm = ((threadIdx.x >> 6) & 1) * 64, wn = (threadIdx.x >> 7) * 64;

// ========== 128x128 core, 8 waves (512 thr): wave tile 32x64, 64 KiB LDS -> 2 blocks/CU ==========
// (byte-identical to the r4-r7-verified pv core)
__device__ __forceinline__ void mfma_nt_128w8(const u16* __restrict__ A, int lda,
                                              const u16* __restrict__ Bp, int ldb,
                                              int m0, int n0, int kext,
                                              u16* Sh, floatx4 acc[2][4])
{
    const int tid  = threadIdx.x;          // 0..511
    const int lane = tid & 63;
    const int lr   = lane & 15, quad = lane >> 4;
    const int wid  = tid >> 6;             // 0..7
    const int wm   = (wid >> 1) * 32;      // 0,32,64,96
    const int wn   = (wid & 1) * 64;       // 0,64
    const int nt   = kext >> 6;

    auto stage4 = [&](int t) {             // 4 gl_lds / thread (512 thr cover 128x32/chunk)
#pragma unroll
        for (int h = 0; h < 4; ++h) {
            const int kk = h >> 1, mat = h & 1;
            const int idx = tid * 8;       // 0..4095 -> full 128x32 plane
            const int row = idx >> 5;
            const int s   = (idx & 31) >> 3;
            const int gk  = (t << 6) + kk * 32 + ((s ^ ((row >> 1) & 3)) << 3);
            u16* dst = Sh + (t & 1) * 16384 + mat * 8192 + kk * 4096 + idx;
            const u16* src = mat ? &Bp[(size_t)(n0 + row) * ldb + gk]
                                 : &A [(size_t)(m0 + row) * lda + gk];
            gl_lds16(src, dst);
        }
    };

    stage4(0);
    for (int t = 0; t < nt; ++t) {
        asm volatile("s_waitcnt vmcnt(0)" ::: "memory");
        __builtin_amdgcn_s_barrier();
        if (t + 1 < nt) stage4(t + 1);
        const u16* buf = Sh + (t & 1) * 16384;
#pragma unroll
        for (int kk = 0; kk < 2; ++kk) {
            short8 af[2], bf[4];
#pragma unroll
            for (int i = 0; i < 2; ++i) {
                const int ar = wm + i * 16 + lr;
                af[i] = *(const short8*)&buf[kk * 4096 + ar * 32 + ((quad ^ ((ar >> 1) & 3)) << 3)];
            }
#pragma unroll
            for (int j = 0; j < 4; ++j) {
                const int br = wn + j * 16 + lr;
                bf[j] = *(const short8*)&buf[8192 + kk * 4096 + br * 32 + ((quad ^ ((br >> 1) & 3)) << 3)];
            }
            __builtin_amdgcn_s_setprio(1);
#pragma unroll
            for (int i = 0; i < 2; ++i)
#pragma unroll
                for (int j = 0; j < 4; ++j)
                    acc[i][j] = __builtin_amdgcn_mfma_f32_16x16x32_bf16(af[i], bf[j], acc[i][j], 0, 0, 0);
            __builtin_amdgcn_s_setprio(0);
        }
    }
}

#define EPIW8_VARS                                            \
    const int lane = threadIdx.x & 63;                        \
    const int lr = lane & 15, quad = lane >> 4;               \
    const int wid = threadIdx.x >> 6;                         \
    const int wm = (wid >> 1) * 32, wn = (wid & 1) * 64;

// ---------------- K1: Mt = Wk *NT* Wq ----------------
__global__ __launch_bounds__(256) void mt_mfma(const u16* __restrict__ Wkb, const u16* __restrict__ Wqb,
                                               u16* __restrict__ Mt)
{
    __shared__ u16 Sh[32768];
    const int m0 = blockIdx.y * 128, n0 = blockIdx.x * 128;
    floatx4 acc[4][4];
#pragma unroll
    for (int i = 0; i < 4; ++i)
#pragma unroll
        for (int j = 0; j < 4; ++j) acc[i][j] = (floatx4){0.f, 0.f, 0.f, 0.f};
    mfma_nt_128(Wkb, D_, Wqb, D_, m0, n0, D_, Sh, acc);

    EPI_VARS
#pragma unroll
    for (int i = 0; i < 4; ++i)
#pragma unroll
        for (int j = 0; j < 4; ++j)
#pragma unroll
            for (int r = 0; r < 4; ++r)
                Mt[(size_t)(m0 + wm + i * 16 + quad * 4 + r) * D_ + n0 + wn + j * 16 + lr] = f2bf(acc[i][j][r]);
}

// ---------------- K2+K3: 1024 blocks of 128^2 on the w8 core (2 blocks/CU co-res) ----------------
// lid<512: Y tile (m=lid>>3, n=lid&7). lid>=512: V tile (b, mloc, n).
// xcd_chunk: XCDs 0-3 own Y tiles, 4-7 own V tiles -> per-XCD L2 holds its panels.
__global__ __launch_bounds__(512, 2) void yv_mfma(const u16* __restrict__ xb, const u16* __restrict__ Mt,
                                                  const u16* __restrict__ Wvt,
                                                  u16* __restrict__ Y, u16* __restrict__ Vt)
{
    __shared__ u16 Sh[32768];                            // 64 KiB
    const int lid = xcd_chunk(blockIdx.x, 1024);
    floatx4 acc[2][4];
#pragma unroll
    for (int i = 0; i < 2; ++i)
#pragma unroll
        for (int j = 0; j < 4; ++j) acc[i][j] = (floatx4){0.f, 0.f, 0.f, 0.f};

    if (lid < 512) {
        const int m0 = (lid >> 3) * 128, n0 = (lid & 7) * 128;
        mfma_nt_128w8(xb, D_, Mt, D_, m0, n0, D_, Sh, acc);
        EPIW8_VARS
#pragma unroll
        for (int i = 0; i < 2; ++i)
#pragma unroll
            for (int j = 0; j < 4; ++j)
#pragma unroll
                for (int r = 0; r < 4; ++r)
                    Y[(size_t)(m0 + wm + i * 16 + quad * 4 + r) * D_ + n0 + wn + j * 16 + lr]
                        = f2bf(acc[i][j][r]);
    } else {
        const int v = lid - 512;
        const int b = v >> 7;
        const int mloc = ((v >> 3) & 15) * 128;
        const int n0 = (v & 7) * 128;
        const int m0 = b * S_ + mloc;
        u16* Vb = Vt + (size_t)b * D_ * S_;
        mfma_nt_128w8(xb, D_, Wvt, D_, m0, n0, D_, Sh, acc);
        EPIW8_VARS
#pragma unroll
        for (int i = 0; i < 2; ++i)
#pragma unroll
            for (int j = 0; j < 4; ++j) {
                const int ee = n0 + wn + j * 16 + lr;
                const int s4 = mloc + wm + i * 16 + quad * 4;   // 4 contiguous s
                ushort4 o;
                o.x = f2bf(acc[i][j][0]); o.y = f2bf(acc[i][j][1]);
                o.z = f2bf(acc[i][j][2]); o.w = f2bf(acc[i][j][3]);
                *(ushort4*)&Vb[(size_t)ee * S_ + s4] = o;       // 8B aligned
            }
    }
}

// ---------------- K4: Sc, 128-granular causal triangle: 544 blocks (2.1/CU) ----------------
__global__ __launch_bounds__(512, 2) void scores_mfma(const u16* __restrict__ Y, const u16* __restrict__ xb,
                                                      u16* __restrict__ Sc)
{
    __shared__ u16 Sh[32768];
    const int lid = xcd_chunk(blockIdx.x, 544);
    const int b = lid / 136;
    const int t = lid - b * 136;
    int qt = (int)((sqrtf(8.0f * t + 1.0f) - 1.0f) * 0.5f);
    while ((qt + 1) * (qt + 2) / 2 <= t) ++qt;
    while (qt * (qt + 1) / 2 > t) --qt;
    const int kt = t - qt * (qt + 1) / 2;

    const u16* A  = Y  + (size_t)b * S_ * D_;
    const u16* Bp = xb + (size_t)b * S_ * D_;
    u16* Sb = Sc + (size_t)b * S_ * S_;
    const int m0 = qt * 128, n0 = kt * 128;
    floatx4 acc[2][4];
#pragma unroll
    for (int i = 0; i < 2; ++i)
#pragma unroll
        for (int j = 0; j < 4; ++j) acc[i][j] = (floatx4){0.f, 0.f, 0.f, 0.f};
    mfma_nt_128w8(A, D_, Bp, D_, m0, n0, D_, Sh, acc);

    EPIW8_VARS
#pragma unroll
    for (int i = 0; i < 2; ++i)
#pragma unroll
        for (int r = 0; r < 4; ++r) {
            const int grow = m0 + wm + i * 16 + quad * 4 + r;
#pragma unroll
            for (int j = 0; j < 4; ++j) {
                const int gcol = n0 + wn + j * 16 + lr;
                const float v = (gcol <= grow) ? acc[i][j][r] * SCALE : NEGINF;
                Sb[(size_t)grow * S_ + gcol] = f2bf(v);
            }
        }
}

// ---------------- K5: row softmax, wave-per-row (no LDS, butterfly shfl) ----------------
__global__ __launch_bounds__(256) void softmax_k(const u16* __restrict__ Sc, u16* __restrict__ P)
{
    const int row = blockIdx.x * 4 + (threadIdx.x >> 6);
    const int lane = threadIdx.x & 63;
    const int b = row >> 11, q = row & (S_ - 1);
    const int L = ((q >> 7) + 1) << 7;           // 128-granular causal span
    const u16* rp = Sc + ((size_t)b * S_ + q) * S_;
    u16* pp = P + ((size_t)b * S_ + q) * S_;

    float f[4][8];
    float lmax = -3.4e38f;
#pragma unroll
    for (int c = 0; c < 4; ++c) {
        const int i = c * 512 + lane * 8;
        if (i < L) {
            short8 v = *(const short8*)&rp[i];
#pragma unroll
            for (int k = 0; k < 8; ++k) { f[c][k] = bf2f((u16)v[k]); lmax = fmaxf(lmax, f[c][k]); }
        }
    }
#pragma unroll
    for (int off = 32; off; off >>= 1) lmax = fmaxf(lmax, __shfl_xor(lmax, off, 64));

    float lsum = 0.f;
#pragma unroll
    for (int c = 0; c < 4; ++c) {
        const int i = c * 512 + lane * 8;
        if (i < L) {
#pragma unroll
            for (int k = 0; k < 8; ++k) { f[c][k] = __expf(f[c][k] - lmax); lsum += f[c][k]; }
        }
    }
#pragma unroll
    for (int off = 32; off; off >>= 1) lsum += __shfl_xor(lsum, off, 64);
    const float inv = 1.0f / lsum;

#pragma unroll
    for (int c = 0; c < 4; ++c) {
        const int i = c * 512 + lane * 8;
        if (i < L) {
            short8 o;
#pragma unroll
            for (int k = 0; k < 8; ++k) o[k] = (short)f2bf(f[c][k] * inv);
            *(short8*)&pp[i] = o;
        }
    }
}

// ---------------- K6: O = P Vt^T: 512 blocks (2/CU co-res), balanced qt ordering ----------------
// lid = s*32 + (b*8+et); a CU's two blocks are lids (j, j+32) -> consecutive s.
// qt(2m)=m, qt(2m+1)=15-m: any consecutive-s pair sums to 17-18 K-tiles.
__global__ __launch_bounds__(512, 2) void pv_mfma(const u16* __restrict__ P, const u16* __restrict__ Vt,
                                                  float* __restrict__ O)
{
    __shared__ u16 Sh[32768];                  // 64 KiB
    const int lid = xcd_chunk(blockIdx.x, 512);
    const int s  = lid >> 5;                   // 0..15
    const int be = lid & 31;
    const int b  = be >> 3, et = be & 7;
    const int qt = (s & 1) ? 15 - (s >> 1) : (s >> 1);
    const int m0 = qt * 128, n0 = et * 128;
    const int kext = (qt + 1) * 128;
    const u16* A  = P  + (size_t)b * S_ * S_;
    const u16* Bp = Vt + (size_t)b * D_ * S_;

    floatx4 acc[2][4];
#pragma unroll
    for (int i = 0; i < 2; ++i)
#pragma unroll
        for (int j = 0; j < 4; ++j) acc[i][j] = (floatx4){0.f, 0.f, 0.f, 0.f};
    mfma_nt_128w8(A, S_, Bp, S_, m0, n0, kext, Sh, acc);

    EPIW8_VARS
#pragma unroll
    for (int i = 0; i < 2; ++i)
#pragma unroll
        for (int r = 0; r < 4; ++r) {
            const int grow = m0 + wm + i * 16 + quad * 4 + r;
#pragma unroll
            for (int j = 0; j < 4; ++j)
                O[((size_t)b * S_ + grow) * D_ + n0 + wn + j * 16 + lr] = acc[i][j][r];
        }
}

extern "C" void kernel_launch(void* const* d_in, const int* in_sizes, int n_in,
                              void* d_out, int out_size, void* d_ws, size_t ws_size,
                              hipStream_t stream) {
    const float* x  = (const float*)d_in[0];
    const float* Wq = (const float*)d_in[1];
    const float* Wk = (const float*)d_in[2];
    const float* Wv = (const float*)d_in[3];
    float* out = (float*)d_out;
    char* w = (char*)d_ws;

    u16* xb  = (u16*)(w);                    // 16.8 MB
    u16* Wqb = (u16*)(w + 16777216);         //  2 MB
    u16* Wkb = (u16*)(w + 18874368);         //  2 MB
    u16* Wvt = (u16*)(w + 20971520);         //  2 MB
    u16* Mt  = (u16*)(w + 23068672);         //  2 MB
    u16* Y   = (u16*)(w + 25165824);         // 16.8 MB
    u16* Vt  = (u16*)(w + 41943040);         // 16.8 MB
    u16* Sc  = (u16*)(w + 58720256);         // 33.5 MB
    u16* P   = (u16*)(w + 92274688);         // 33.5 MB

    cast_fused <<<dim3(6144),   256, 0, stream>>>(x, Wq, Wk, Wv, xb, Wqb, Wkb, Wvt);
    mt_mfma    <<<dim3(8, 8),   256, 0, stream>>>(Wkb, Wqb, Mt);
    yv_mfma    <<<dim3(1024),   512, 0, stream>>>(xb, Mt, Wvt, Y, Vt);
    scores_mfma<<<dim3(544),    512, 0, stream>>>(Y, xb, Sc);
    softmax_k  <<<dim3(N_/4),   256, 0, stream>>>(Sc, P);
    pv_mfma    <<<dim3(512),    512, 0, stream>>>(P, Vt, out);
}